// Round 1
// baseline (205.409 us; speedup 1.0000x reference)
//
#include <hip/hip_runtime.h>

#define KDIM 1024
#define NDIM 16384
#define CHUNKS 256
#define CLEN 64   // NDIM / CHUNKS

typedef __bf16 bf16_t;
typedef bf16_t bf16x8 __attribute__((ext_vector_type(8)));
typedef bf16_t bf16x4 __attribute__((ext_vector_type(4)));
typedef float f32x4 __attribute__((ext_vector_type(4)));

// ---------------- halpha fp32 -> bf16 ----------------
__global__ __launch_bounds__(256) void k_convert_alpha(const float* __restrict__ A,
                                                       bf16_t* __restrict__ Ab) {
  size_t i = ((size_t)blockIdx.x * 256 + threadIdx.x) * 4;
  float4 v = *reinterpret_cast<const float4*>(A + i);
  bf16x4 o;
  o[0] = (bf16_t)v.x; o[1] = (bf16_t)v.y; o[2] = (bf16_t)v.z; o[3] = (bf16_t)v.w;
  *reinterpret_cast<bf16x4*>(Ab + i) = o;
}

// ---------------- scan phase 1: chunk-local carries + row partial sums ----------------
__global__ __launch_bounds__(256) void k_phase1(const float* __restrict__ obs,
                                                const float* __restrict__ hbeta,
                                                float* __restrict__ carry,
                                                float* __restrict__ psum) {
  int tid = blockIdx.x * 256 + threadIdx.x;   // 0 .. K*CHUNKS-1
  int k = tid >> 8;                            // / CHUNKS
  int c = tid & (CHUNKS - 1);
  float beta = hbeta[0];
  float decay = expf(-beta);
  const float* p = obs + (size_t)k * NDIM + c * CLEN;
  float S = 0.f, sum = 0.f;
#pragma unroll
  for (int t = 0; t < CLEN; t += 4) {
    float4 v = *reinterpret_cast<const float4*>(p + t);
    S = decay * (S + beta * v.x);
    S = decay * (S + beta * v.y);
    S = decay * (S + beta * v.z);
    S = decay * (S + beta * v.w);
    sum += v.x + v.y + v.z + v.w;
  }
  carry[tid] = S;   // layout [k][c]
  psum[tid] = sum;
}

// ---------------- scan phase 2: exclusive prefix over chunk carries; hmu ----------------
__global__ __launch_bounds__(256) void k_phase2(const float* __restrict__ hbeta,
                                                float* __restrict__ carry,
                                                const float* __restrict__ psum,
                                                float* __restrict__ hmu) {
  int k = blockIdx.x * blockDim.x + threadIdx.x;
  if (k >= KDIM) return;
  float beta = hbeta[0];
  float dL = expf(-beta * (float)CLEN);   // decay^CLEN
  float Cg = 0.f, tot = 0.f;
  float* pc = carry + (size_t)k * CHUNKS;
  const float* pp = psum + (size_t)k * CHUNKS;
  for (int c = 0; c < CHUNKS; ++c) {
    float loc = pc[c];
    pc[c] = Cg;               // global S at chunk start
    Cg = dL * Cg + loc;
    tot += pp[c];
  }
  hmu[k] = tot * (1.0f / NDIM) * 0.1f + 0.01f;
}

// ---------------- scan phase 3: full scan with carry, write S_all [t][j] bf16 ----------------
__global__ __launch_bounds__(64) void k_phase3(const float* __restrict__ obs,
                                               const float* __restrict__ hbeta,
                                               const float* __restrict__ carry,
                                               bf16_t* __restrict__ S_all) {
  int c  = blockIdx.x & (CHUNKS - 1);
  int kb = blockIdx.x >> 8;
  int lane = threadIdx.x;
  float beta = hbeta[0];
  float decay = expf(-beta);
  __shared__ float  obs_s[64][65];
  __shared__ bf16_t out_s[64][72];
  int k0 = kb * 64, t0 = c * CLEN;
  // coalesced load of obs tile [64 k-rows][64 t]
#pragma unroll 4
  for (int r = 0; r < 64; ++r)
    obs_s[r][lane] = obs[(size_t)(k0 + r) * NDIM + t0 + lane];
  __syncthreads();
  float S = carry[(size_t)(k0 + lane) * CHUNKS + c];
#pragma unroll 8
  for (int t = 0; t < CLEN; ++t) {
    out_s[t][lane] = (bf16_t)S;                 // S_all[t] is pre-update value
    S = decay * (S + beta * obs_s[lane][t]);
  }
  __syncthreads();
  // coalesced transposed store: wave writes 64 contiguous bf16 per t
#pragma unroll 4
  for (int t = 0; t < CLEN; ++t)
    S_all[(size_t)(t0 + t) * KDIM + k0 + lane] = out_s[t][lane];
}

// ---------------- GEMM lam1 = halpha @ S_all^T, fused softplus + loglik ----------------
__global__ __launch_bounds__(256) void k_gemm(const bf16_t* __restrict__ Ab,
                                              const bf16_t* __restrict__ Bb,
                                              const float* __restrict__ hmu,
                                              const float* __restrict__ obs,
                                              float* __restrict__ out) {
  __shared__ bf16_t As[128 * 32];
  __shared__ bf16_t Bs[128 * 32];
  int tid = threadIdx.x;
  int bid = blockIdx.x;
  int kb = bid >> 7;         // M-tile (8)
  int tb = bid & 127;        // N-tile (128)
  int lane = tid & 63, wid = tid >> 6;
  int wm = wid >> 1, wn = wid & 1;          // 2x2 waves, each 64x64
  int r15 = lane & 15, h = lane >> 4;
  f32x4 acc[4][4] = {};

  for (int kk = 0; kk < KDIM; kk += 32) {
#pragma unroll
    for (int it = 0; it < 2; ++it) {
      int idx8 = it * 256 + tid;            // 0..511 groups of 8 bf16
      int row = idx8 >> 2, col8 = idx8 & 3;
      uint4 va = *reinterpret_cast<const uint4*>(Ab + (size_t)(kb * 128 + row) * KDIM + kk + col8 * 8);
      uint4 vb = *reinterpret_cast<const uint4*>(Bb + (size_t)(tb * 128 + row) * KDIM + kk + col8 * 8);
      *reinterpret_cast<uint4*>(&As[(size_t)idx8 * 8]) = va;
      *reinterpret_cast<uint4*>(&Bs[(size_t)idx8 * 8]) = vb;
    }
    __syncthreads();
    bf16x8 af[4], bfr[4];
#pragma unroll
    for (int mi = 0; mi < 4; ++mi)
      af[mi] = *reinterpret_cast<const bf16x8*>(&As[(wm * 64 + mi * 16 + r15) * 32 + h * 8]);
#pragma unroll
    for (int ni = 0; ni < 4; ++ni)
      bfr[ni] = *reinterpret_cast<const bf16x8*>(&Bs[(wn * 64 + ni * 16 + r15) * 32 + h * 8]);
#pragma unroll
    for (int mi = 0; mi < 4; ++mi)
#pragma unroll
      for (int ni = 0; ni < 4; ++ni)
        acc[mi][ni] = __builtin_amdgcn_mfma_f32_16x16x32_bf16(af[mi], bfr[ni], acc[mi][ni], 0, 0, 0);
    __syncthreads();
  }

  // epilogue: lams = softplus(hmu + lam1); loglik partial = obs*log(lams) - lams
  float lsum = 0.f;
  float* lams = out + 1;
#pragma unroll
  for (int mi = 0; mi < 4; ++mi) {
    int krow0 = kb * 128 + wm * 64 + mi * 16 + h * 4;
#pragma unroll
    for (int ni = 0; ni < 4; ++ni) {
      int t = tb * 128 + wn * 64 + ni * 16 + r15;
#pragma unroll
      for (int r = 0; r < 4; ++r) {
        int krow = krow0 + r;
        float x = hmu[krow] + acc[mi][ni][r];
        float lam = (x > 15.f) ? x : log1pf(__expf(x));
        lams[(size_t)krow * NDIM + t] = lam;
        float o = obs[(size_t)krow * NDIM + t];
        lsum += o * __logf(lam) - lam;
      }
    }
  }
  // reduce loglik
  lsum += __shfl_down(lsum, 32);
  lsum += __shfl_down(lsum, 16);
  lsum += __shfl_down(lsum, 8);
  lsum += __shfl_down(lsum, 4);
  lsum += __shfl_down(lsum, 2);
  lsum += __shfl_down(lsum, 1);
  __shared__ float wsum[4];
  if (lane == 0) wsum[wid] = lsum;
  __syncthreads();
  if (tid == 0) atomicAdd(out, wsum[0] + wsum[1] + wsum[2] + wsum[3]);
}

extern "C" void kernel_launch(void* const* d_in, const int* in_sizes, int n_in,
                              void* d_out, int out_size, void* d_ws, size_t ws_size,
                              hipStream_t stream) {
  const float* obs    = (const float*)d_in[0];
  const float* halpha = (const float*)d_in[1];
  const float* hbeta  = (const float*)d_in[2];
  float* out = (float*)d_out;

  char* ws = (char*)d_ws;
  bf16_t* S_all = (bf16_t*)ws;                                   // 32 MB, [NDIM][KDIM]
  float*  carry = (float*)(ws + (size_t)NDIM * KDIM * 2);        // 1 MB, [K][CHUNKS]
  float*  psum  = carry + (size_t)KDIM * CHUNKS;                 // 1 MB
  float*  hmu   = psum + (size_t)KDIM * CHUNKS;                  // 4 KB
  bf16_t* Ab    = (bf16_t*)(hmu + KDIM);                         // 2 MB

  hipMemsetAsync(d_out, 0, sizeof(float), stream);               // loglik accumulator
  k_convert_alpha<<<(KDIM * KDIM) / (256 * 4), 256, 0, stream>>>(halpha, Ab);
  k_phase1<<<(KDIM * CHUNKS) / 256, 256, 0, stream>>>(obs, hbeta, carry, psum);
  k_phase2<<<4, 256, 0, stream>>>(hbeta, carry, psum, hmu);
  k_phase3<<<(KDIM / 64) * CHUNKS, 64, 0, stream>>>(obs, hbeta, carry, S_all);
  k_gemm<<<(KDIM / 128) * (NDIM / 128), 256, 0, stream>>>(Ab, S_all, hmu, obs, out);
}

// Round 2
// 179.292 us; speedup vs baseline: 1.1457x; 1.1457x over previous
//
#include <hip/hip_runtime.h>

#define KDIM 1024
#define NDIM 16384
#define CHUNKS 256
#define CLEN 64   // NDIM / CHUNKS

typedef __bf16 bf16_t;
typedef bf16_t bf16x8 __attribute__((ext_vector_type(8)));
typedef bf16_t bf16x4 __attribute__((ext_vector_type(4)));
typedef float f32x4 __attribute__((ext_vector_type(4)));

__device__ __forceinline__ void gload_lds16(const bf16_t* g, bf16_t* l) {
  __builtin_amdgcn_global_load_lds(
      (const __attribute__((address_space(1))) void*)g,
      (__attribute__((address_space(3))) void*)l, 16, 0, 0);
}

// ---------------- halpha fp32 -> bf16 ----------------
__global__ __launch_bounds__(256) void k_convert_alpha(const float* __restrict__ A,
                                                       bf16_t* __restrict__ Ab) {
  size_t i = ((size_t)blockIdx.x * 256 + threadIdx.x) * 4;
  float4 v = *reinterpret_cast<const float4*>(A + i);
  bf16x4 o;
  o[0] = (bf16_t)v.x; o[1] = (bf16_t)v.y; o[2] = (bf16_t)v.z; o[3] = (bf16_t)v.w;
  *reinterpret_cast<bf16x4*>(Ab + i) = o;
}

// ---------------- scan phase 1: chunk-local carries + row partial sums ----------------
__global__ __launch_bounds__(256) void k_phase1(const float* __restrict__ obs,
                                                const float* __restrict__ hbeta,
                                                float* __restrict__ carry,
                                                float* __restrict__ psum) {
  int tid = blockIdx.x * 256 + threadIdx.x;   // 0 .. K*CHUNKS-1
  int k = tid >> 8;                            // / CHUNKS
  int c = tid & (CHUNKS - 1);
  float beta = hbeta[0];
  float decay = expf(-beta);
  const float* p = obs + (size_t)k * NDIM + c * CLEN;
  float S = 0.f, sum = 0.f;
#pragma unroll
  for (int t = 0; t < CLEN; t += 4) {
    float4 v = *reinterpret_cast<const float4*>(p + t);
    S = decay * (S + beta * v.x);
    S = decay * (S + beta * v.y);
    S = decay * (S + beta * v.z);
    S = decay * (S + beta * v.w);
    sum += v.x + v.y + v.z + v.w;
  }
  carry[tid] = S;   // layout [k][c]
  psum[tid] = sum;
}

// ---------------- scan phase 2: exclusive prefix over chunk carries; hmu ----------------
__global__ __launch_bounds__(64) void k_phase2(const float* __restrict__ hbeta,
                                               float* __restrict__ carry,
                                               const float* __restrict__ psum,
                                               float* __restrict__ hmu) {
  int k = blockIdx.x * blockDim.x + threadIdx.x;
  if (k >= KDIM) return;
  float beta = hbeta[0];
  float dL = expf(-beta * (float)CLEN);   // decay^CLEN
  float Cg = 0.f, tot = 0.f;
  float* pc = carry + (size_t)k * CHUNKS;
  const float* pp = psum + (size_t)k * CHUNKS;
  for (int c = 0; c < CHUNKS; ++c) {
    float loc = pc[c];
    pc[c] = Cg;               // global S at chunk start
    Cg = dL * Cg + loc;
    tot += pp[c];
  }
  hmu[k] = tot * (1.0f / NDIM) * 0.1f + 0.01f;
}

// ---------------- scan phase 3: full scan with carry, write S_all [t][j] bf16 ----------------
__global__ __launch_bounds__(64) void k_phase3(const float* __restrict__ obs,
                                               const float* __restrict__ hbeta,
                                               const float* __restrict__ carry,
                                               bf16_t* __restrict__ S_all) {
  int c  = blockIdx.x & (CHUNKS - 1);
  int kb = blockIdx.x >> 8;
  int lane = threadIdx.x;
  float beta = hbeta[0];
  float decay = expf(-beta);
  __shared__ float  obs_s[64][65];
  __shared__ bf16_t out_s[64][72];
  int k0 = kb * 64, t0 = c * CLEN;
  // coalesced load of obs tile [64 k-rows][64 t]
#pragma unroll 4
  for (int r = 0; r < 64; ++r)
    obs_s[r][lane] = obs[(size_t)(k0 + r) * NDIM + t0 + lane];
  __syncthreads();
  float S = carry[(size_t)(k0 + lane) * CHUNKS + c];
#pragma unroll 8
  for (int t = 0; t < CLEN; ++t) {
    out_s[t][lane] = (bf16_t)S;                 // S_all[t] is pre-update value
    S = decay * (S + beta * obs_s[lane][t]);
  }
  __syncthreads();
  // coalesced transposed store: wave writes 64 contiguous bf16 per t
#pragma unroll 4
  for (int t = 0; t < CLEN; ++t)
    S_all[(size_t)(t0 + t) * KDIM + k0 + lane] = out_s[t][lane];
}

// ---------------- GEMM lam1 = halpha @ S_all^T, fused softplus + loglik ----------------
__global__ __launch_bounds__(256) void k_gemm(const bf16_t* __restrict__ Ab,
                                              const bf16_t* __restrict__ Bb,
                                              const float* __restrict__ hmu,
                                              const float* __restrict__ obs,
                                              float* __restrict__ out) {
  __shared__ bf16_t As[128 * 32];
  __shared__ bf16_t Bs[128 * 32];
  int tid = threadIdx.x;
  int bid = blockIdx.x;
  int kb = bid >> 7;         // M-tile (8)
  int tb = bid & 127;        // N-tile (128)
  int lane = tid & 63, wid = tid >> 6;
  int wm = wid >> 1, wn = wid & 1;          // 2x2 waves, each 64x64
  int r15 = lane & 15, h = lane >> 4;
  f32x4 acc[4][4] = {};

  // staging addresses: issue `it` covers idx8 = it*256 + tid; row = idx8>>2, col8 = idx8&3
  int row0 = tid >> 2, col8 = tid & 3;
  const bf16_t* gA0 = Ab + (size_t)(kb * 128 + row0) * KDIM + col8 * 8;
  const bf16_t* gA1 = gA0 + (size_t)64 * KDIM;
  const bf16_t* gB0 = Bb + (size_t)(tb * 128 + row0) * KDIM + col8 * 8;
  const bf16_t* gB1 = gB0 + (size_t)64 * KDIM;
  bf16_t* lA0 = &As[(wid * 64) * 8];        // wave-uniform LDS bases (lane*16B added by HW)
  bf16_t* lA1 = &As[(256 + wid * 64) * 8];
  bf16_t* lB0 = &Bs[(wid * 64) * 8];
  bf16_t* lB1 = &Bs[(256 + wid * 64) * 8];

  for (int kk = 0; kk < KDIM; kk += 32) {
    gload_lds16(gA0 + kk, lA0);
    gload_lds16(gA1 + kk, lA1);
    gload_lds16(gB0 + kk, lB0);
    gload_lds16(gB1 + kk, lB1);
    __syncthreads();
    bf16x8 af[4], bfr[4];
#pragma unroll
    for (int mi = 0; mi < 4; ++mi)
      af[mi] = *reinterpret_cast<const bf16x8*>(&As[(wm * 64 + mi * 16 + r15) * 32 + h * 8]);
#pragma unroll
    for (int ni = 0; ni < 4; ++ni)
      bfr[ni] = *reinterpret_cast<const bf16x8*>(&Bs[(wn * 64 + ni * 16 + r15) * 32 + h * 8]);
#pragma unroll
    for (int mi = 0; mi < 4; ++mi)
#pragma unroll
      for (int ni = 0; ni < 4; ++ni)
        acc[mi][ni] = __builtin_amdgcn_mfma_f32_16x16x32_bf16(af[mi], bfr[ni], acc[mi][ni], 0, 0, 0);
    __syncthreads();
  }

  // epilogue: lams = softplus(hmu + lam1); loglik partial = obs*log(lams) - lams
  float lsum = 0.f;
  float* lams = out + 1;
#pragma unroll
  for (int mi = 0; mi < 4; ++mi) {
    int krow0 = kb * 128 + wm * 64 + mi * 16 + h * 4;
#pragma unroll
    for (int ni = 0; ni < 4; ++ni) {
      int t = tb * 128 + wn * 64 + ni * 16 + r15;
#pragma unroll
      for (int r = 0; r < 4; ++r) {
        int krow = krow0 + r;
        float x = hmu[krow] + acc[mi][ni][r];
        float lam = (x > 15.f) ? x : log1pf(__expf(x));
        lams[(size_t)krow * NDIM + t] = lam;
        float o = obs[(size_t)krow * NDIM + t];
        lsum += o * __logf(lam) - lam;
      }
    }
  }
  // reduce loglik
  lsum += __shfl_down(lsum, 32);
  lsum += __shfl_down(lsum, 16);
  lsum += __shfl_down(lsum, 8);
  lsum += __shfl_down(lsum, 4);
  lsum += __shfl_down(lsum, 2);
  lsum += __shfl_down(lsum, 1);
  __shared__ float wsum[4];
  if (lane == 0) wsum[wid] = lsum;
  __syncthreads();
  if (tid == 0) atomicAdd(out, wsum[0] + wsum[1] + wsum[2] + wsum[3]);
}

extern "C" void kernel_launch(void* const* d_in, const int* in_sizes, int n_in,
                              void* d_out, int out_size, void* d_ws, size_t ws_size,
                              hipStream_t stream) {
  const float* obs    = (const float*)d_in[0];
  const float* halpha = (const float*)d_in[1];
  const float* hbeta  = (const float*)d_in[2];
  float* out = (float*)d_out;

  char* ws = (char*)d_ws;
  bf16_t* S_all = (bf16_t*)ws;                                   // 32 MB, [NDIM][KDIM]
  float*  carry = (float*)(ws + (size_t)NDIM * KDIM * 2);        // 1 MB, [K][CHUNKS]
  float*  psum  = carry + (size_t)KDIM * CHUNKS;                 // 1 MB
  float*  hmu   = psum + (size_t)KDIM * CHUNKS;                  // 4 KB
  bf16_t* Ab    = (bf16_t*)(hmu + KDIM);                         // 2 MB

  hipMemsetAsync(d_out, 0, sizeof(float), stream);               // loglik accumulator
  k_convert_alpha<<<(KDIM * KDIM) / (256 * 4), 256, 0, stream>>>(halpha, Ab);
  k_phase1<<<(KDIM * CHUNKS) / 256, 256, 0, stream>>>(obs, hbeta, carry, psum);
  k_phase2<<<16, 64, 0, stream>>>(hbeta, carry, psum, hmu);
  k_phase3<<<(KDIM / 64) * CHUNKS, 64, 0, stream>>>(obs, hbeta, carry, S_all);
  k_gemm<<<(KDIM / 128) * (NDIM / 128), 256, 0, stream>>>(Ab, S_all, hmu, obs, out);
}

// Round 3
// 175.786 us; speedup vs baseline: 1.1685x; 1.0199x over previous
//
#include <hip/hip_runtime.h>

#define KDIM 1024
#define NDIM 16384
#define CHUNKS 256
#define CLEN 64   // NDIM / CHUNKS
#define KTILES 16 // KDIM / 64

typedef __bf16 bf16_t;
typedef bf16_t bf16x8 __attribute__((ext_vector_type(8)));
typedef bf16_t bf16x4 __attribute__((ext_vector_type(4)));
typedef float f32x4 __attribute__((ext_vector_type(4)));

__device__ __forceinline__ void gload_lds16(const bf16_t* g, bf16_t* l) {
  __builtin_amdgcn_global_load_lds(
      (const __attribute__((address_space(1))) void*)g,
      (__attribute__((address_space(3))) void*)l, 16, 0, 0);
}

// ---------------- halpha fp32 -> bf16 ----------------
__global__ __launch_bounds__(256) void k_convert_alpha(const float* __restrict__ A,
                                                       bf16_t* __restrict__ Ab) {
  size_t i = ((size_t)blockIdx.x * 256 + threadIdx.x) * 4;
  float4 v = *reinterpret_cast<const float4*>(A + i);
  bf16x4 o;
  o[0] = (bf16_t)v.x; o[1] = (bf16_t)v.y; o[2] = (bf16_t)v.z; o[3] = (bf16_t)v.w;
  *reinterpret_cast<bf16x4*>(Ab + i) = o;
}

// ---------------- scan phase 1: chunk-local carries + row partial sums ----------------
__global__ __launch_bounds__(256) void k_phase1(const float* __restrict__ obs,
                                                const float* __restrict__ hbeta,
                                                float* __restrict__ carry,
                                                float* __restrict__ psum) {
  int tid = blockIdx.x * 256 + threadIdx.x;   // 0 .. K*CHUNKS-1
  int k = tid >> 8;                            // / CHUNKS
  int c = tid & (CHUNKS - 1);
  float beta = hbeta[0];
  float decay = expf(-beta);
  const float* p = obs + (size_t)k * NDIM + c * CLEN;
  float S = 0.f, sum = 0.f;
#pragma unroll
  for (int t = 0; t < CLEN; t += 4) {
    float4 v = *reinterpret_cast<const float4*>(p + t);
    S = decay * (S + beta * v.x);
    S = decay * (S + beta * v.y);
    S = decay * (S + beta * v.z);
    S = decay * (S + beta * v.w);
    sum += v.x + v.y + v.z + v.w;
  }
  carry[tid] = S;   // layout [k][c]
  psum[tid] = sum;
}

// ---------------- scan phase 2: exclusive prefix over chunk carries; hmu ----------------
__global__ __launch_bounds__(64) void k_phase2(const float* __restrict__ hbeta,
                                               float* __restrict__ carry,
                                               const float* __restrict__ psum,
                                               float* __restrict__ hmu) {
  int k = blockIdx.x * blockDim.x + threadIdx.x;
  if (k >= KDIM) return;
  float beta = hbeta[0];
  float dL = expf(-beta * (float)CLEN);   // decay^CLEN
  float Cg = 0.f, tot = 0.f;
  float* pc = carry + (size_t)k * CHUNKS;
  const float* pp = psum + (size_t)k * CHUNKS;
  for (int c = 0; c < CHUNKS; ++c) {
    float loc = pc[c];
    pc[c] = Cg;               // global S at chunk start
    Cg = dL * Cg + loc;
    tot += pp[c];
  }
  hmu[k] = tot * (1.0f / NDIM) * 0.1f + 0.01f;
}

// ---------------- scan phase 3: full scan with carry, write S_all [t][j] bf16 ----------------
__global__ __launch_bounds__(64) void k_phase3(const float* __restrict__ obs,
                                               const float* __restrict__ hbeta,
                                               const float* __restrict__ carry,
                                               bf16_t* __restrict__ S_all) {
  int c  = blockIdx.x & (CHUNKS - 1);
  int kb = blockIdx.x >> 8;
  int lane = threadIdx.x;
  float beta = hbeta[0];
  float decay = expf(-beta);
  __shared__ float  obs_s[64][65];
  __shared__ bf16_t out_s[64][72];
  int k0 = kb * 64, t0 = c * CLEN;
#pragma unroll 4
  for (int r = 0; r < 64; ++r)
    obs_s[r][lane] = obs[(size_t)(k0 + r) * NDIM + t0 + lane];
  __syncthreads();
  float S = carry[(size_t)(k0 + lane) * CHUNKS + c];
#pragma unroll 8
  for (int t = 0; t < CLEN; ++t) {
    out_s[t][lane] = (bf16_t)S;                 // S_all[t] is pre-update value
    S = decay * (S + beta * obs_s[lane][t]);
  }
  __syncthreads();
#pragma unroll 4
  for (int t = 0; t < CLEN; ++t)
    S_all[(size_t)(t0 + t) * KDIM + k0 + lane] = out_s[t][lane];
}

// ---------------- GEMM lam1 = halpha @ S_all^T, fused softplus + loglik ----------------
// 256x256 tile, BK=64, 512 threads (8 waves, 2M x 4N), double-buffered LDS,
// prefetch one K-tile ahead with counted vmcnt(8). LDS XOR-swizzle (slot ^= row&7)
// applied via pre-swizzled GLOBAL source (gload_lds dest stays linear) + swizzled ds_read.
__global__ __launch_bounds__(512, 2) void k_gemm(const bf16_t* __restrict__ Ab,
                                                 const bf16_t* __restrict__ Bb,
                                                 const float* __restrict__ hmu,
                                                 const float* __restrict__ obs,
                                                 float* __restrict__ out) {
  __shared__ bf16_t As[2][256 * 64];
  __shared__ bf16_t Bs[2][256 * 64];
  int tid = threadIdx.x;
  // XCD-chunk swizzle: 256 blocks, 8 XCDs -> each XCD gets 32 contiguous logical tiles
  int b = blockIdx.x;
  int lb = (b & 7) * 32 + (b >> 3);
  int kb = lb & 3;            // M-tile (4)
  int tb = lb >> 2;           // N-tile (64); 4 consecutive logical blocks share tb (B-panel)
  int lane = tid & 63, wid = tid >> 6;
  int wm = wid >> 2, wn = wid & 3;          // 2x4 waves, each 128x64 output
  int r15 = lane & 15, h = lane >> 4;
  f32x4 acc[8][4] = {};

  // staging: slot_id = i*512 + tid; row = slot_id>>3; phys slot sp = slot_id&7;
  // global source uses logical slot sl = sp ^ (row&7)  (inverse-swizzle the source)
  const bf16_t* gA[4];
  const bf16_t* gB[4];
#pragma unroll
  for (int i = 0; i < 4; ++i) {
    int slot = i * 512 + tid;
    int row = slot >> 3, sp = slot & 7;
    int sl = sp ^ (row & 7);
    gA[i] = Ab + (size_t)(kb * 256 + row) * KDIM + sl * 8;
    gB[i] = Bb + (size_t)(tb * 256 + row) * KDIM + sl * 8;
  }

#define STAGE(buf, kkoff) do { \
  _Pragma("unroll") \
  for (int i = 0; i < 4; ++i) \
    gload_lds16(gA[i] + (kkoff), &As[buf][(i * 512 + wid * 64) * 8]); \
  _Pragma("unroll") \
  for (int i = 0; i < 4; ++i) \
    gload_lds16(gB[i] + (kkoff), &Bs[buf][(i * 512 + wid * 64) * 8]); \
} while (0)

  STAGE(0, 0);
  int cur = 0;
  for (int kt = 0; kt < KTILES; ++kt) {
    if (kt < KTILES - 1) {
      STAGE(cur ^ 1, (kt + 1) * 64);
      asm volatile("s_waitcnt vmcnt(8)" ::: "memory");   // current tile's 8 loads done
    } else {
      asm volatile("s_waitcnt vmcnt(0)" ::: "memory");
    }
    __builtin_amdgcn_s_barrier();
#pragma unroll
    for (int kh = 0; kh < 2; ++kh) {
      bf16x8 af[8], bfr[4];
#pragma unroll
      for (int mi = 0; mi < 8; ++mi) {
        int row = wm * 128 + mi * 16 + r15;
        af[mi] = *reinterpret_cast<const bf16x8*>(
            &As[cur][row * 64 + (((kh * 4 + h) ^ (row & 7)) * 8)]);
      }
#pragma unroll
      for (int ni = 0; ni < 4; ++ni) {
        int row = wn * 64 + ni * 16 + r15;
        bfr[ni] = *reinterpret_cast<const bf16x8*>(
            &Bs[cur][row * 64 + (((kh * 4 + h) ^ (row & 7)) * 8)]);
      }
#pragma unroll
      for (int mi = 0; mi < 8; ++mi)
#pragma unroll
        for (int ni = 0; ni < 4; ++ni)
          acc[mi][ni] = __builtin_amdgcn_mfma_f32_16x16x32_bf16(af[mi], bfr[ni], acc[mi][ni], 0, 0, 0);
    }
    __builtin_amdgcn_s_barrier();   // all waves done reading buf[cur] before overwrite
    cur ^= 1;
  }
#undef STAGE

  // epilogue: lams = softplus(hmu + lam1); loglik partial = obs*log(lams) - lams
  float lsum = 0.f;
  float* lams = out + 1;
#pragma unroll
  for (int mi = 0; mi < 8; ++mi) {
    int krow0 = kb * 256 + wm * 128 + mi * 16 + h * 4;
#pragma unroll
    for (int ni = 0; ni < 4; ++ni) {
      int t = tb * 256 + wn * 64 + ni * 16 + r15;
#pragma unroll
      for (int r = 0; r < 4; ++r) {
        int krow = krow0 + r;
        float x = hmu[krow] + acc[mi][ni][r];
        float lam = (x > 15.f) ? x : log1pf(__expf(x));
        lams[(size_t)krow * NDIM + t] = lam;
        float o = obs[(size_t)krow * NDIM + t];
        lsum += o * __logf(lam) - lam;
      }
    }
  }
  // reduce loglik
  lsum += __shfl_down(lsum, 32);
  lsum += __shfl_down(lsum, 16);
  lsum += __shfl_down(lsum, 8);
  lsum += __shfl_down(lsum, 4);
  lsum += __shfl_down(lsum, 2);
  lsum += __shfl_down(lsum, 1);
  __shared__ float wsum[8];
  if (lane == 0) wsum[wid] = lsum;
  __syncthreads();
  if (tid == 0) {
    float s = 0.f;
#pragma unroll
    for (int w = 0; w < 8; ++w) s += wsum[w];
    atomicAdd(out, s);
  }
}

extern "C" void kernel_launch(void* const* d_in, const int* in_sizes, int n_in,
                              void* d_out, int out_size, void* d_ws, size_t ws_size,
                              hipStream_t stream) {
  const float* obs    = (const float*)d_in[0];
  const float* halpha = (const float*)d_in[1];
  const float* hbeta  = (const float*)d_in[2];
  float* out = (float*)d_out;

  char* ws = (char*)d_ws;
  bf16_t* S_all = (bf16_t*)ws;                                   // 32 MB, [NDIM][KDIM]
  float*  carry = (float*)(ws + (size_t)NDIM * KDIM * 2);        // 1 MB, [K][CHUNKS]
  float*  psum  = carry + (size_t)KDIM * CHUNKS;                 // 1 MB
  float*  hmu   = psum + (size_t)KDIM * CHUNKS;                  // 4 KB
  bf16_t* Ab    = (bf16_t*)(hmu + KDIM);                         // 2 MB

  hipMemsetAsync(d_out, 0, sizeof(float), stream);               // loglik accumulator
  k_convert_alpha<<<(KDIM * KDIM) / (256 * 4), 256, 0, stream>>>(halpha, Ab);
  k_phase1<<<(KDIM * CHUNKS) / 256, 256, 0, stream>>>(obs, hbeta, carry, psum);
  k_phase2<<<16, 64, 0, stream>>>(hbeta, carry, psum, hmu);
  k_phase3<<<(KDIM / 64) * CHUNKS, 64, 0, stream>>>(obs, hbeta, carry, S_all);
  k_gemm<<<4 * (NDIM / 256), 512, 0, stream>>>(Ab, S_all, hmu, obs, out);
}

// Round 4
// 112.653 us; speedup vs baseline: 1.8234x; 1.5604x over previous
//
#include <hip/hip_runtime.h>

#define KDIM 1024
#define NDIM 16384
#define CHUNKS 256
#define CLEN 64   // NDIM / CHUNKS
#define KTILES 16 // KDIM / 64

typedef __bf16 bf16_t;
typedef bf16_t bf16x8 __attribute__((ext_vector_type(8)));
typedef bf16_t bf16x4 __attribute__((ext_vector_type(4)));
typedef float f32x4 __attribute__((ext_vector_type(4)));

__device__ __forceinline__ void gload_lds16(const bf16_t* g, bf16_t* l) {
  __builtin_amdgcn_global_load_lds(
      (const __attribute__((address_space(1))) void*)g,
      (__attribute__((address_space(3))) void*)l, 16, 0, 0);
}

// ---------------- halpha fp32 -> bf16 ----------------
__global__ __launch_bounds__(256) void k_convert_alpha(const float* __restrict__ A,
                                                       bf16_t* __restrict__ Ab) {
  size_t i = ((size_t)blockIdx.x * 256 + threadIdx.x) * 4;
  float4 v = *reinterpret_cast<const float4*>(A + i);
  bf16x4 o;
  o[0] = (bf16_t)v.x; o[1] = (bf16_t)v.y; o[2] = (bf16_t)v.z; o[3] = (bf16_t)v.w;
  *reinterpret_cast<bf16x4*>(Ab + i) = o;
}

// ---------------- scan phase 1: chunk-local carries + row partial sums ----------------
__global__ __launch_bounds__(256) void k_phase1(const float* __restrict__ obs,
                                                const float* __restrict__ hbeta,
                                                float* __restrict__ carry,
                                                float* __restrict__ psum) {
  int tid = blockIdx.x * 256 + threadIdx.x;   // 0 .. K*CHUNKS-1
  int k = tid >> 8;                            // / CHUNKS
  int c = tid & (CHUNKS - 1);
  float beta = hbeta[0];
  float decay = expf(-beta);
  const float* p = obs + (size_t)k * NDIM + c * CLEN;
  float S = 0.f, sum = 0.f;
#pragma unroll
  for (int t = 0; t < CLEN; t += 4) {
    float4 v = *reinterpret_cast<const float4*>(p + t);
    S = decay * (S + beta * v.x);
    S = decay * (S + beta * v.y);
    S = decay * (S + beta * v.z);
    S = decay * (S + beta * v.w);
    sum += v.x + v.y + v.z + v.w;
  }
  carry[tid] = S;   // layout [k][c]
  psum[tid] = sum;
}

// ---------------- scan phase 2: exclusive prefix over chunk carries; hmu ----------------
__global__ __launch_bounds__(64) void k_phase2(const float* __restrict__ hbeta,
                                               float* __restrict__ carry,
                                               const float* __restrict__ psum,
                                               float* __restrict__ hmu) {
  int k = blockIdx.x * blockDim.x + threadIdx.x;
  if (k >= KDIM) return;
  float beta = hbeta[0];
  float dL = expf(-beta * (float)CLEN);   // decay^CLEN
  float Cg = 0.f, tot = 0.f;
  float* pc = carry + (size_t)k * CHUNKS;
  const float* pp = psum + (size_t)k * CHUNKS;
  for (int c = 0; c < CHUNKS; ++c) {
    float loc = pc[c];
    pc[c] = Cg;               // global S at chunk start
    Cg = dL * Cg + loc;
    tot += pp[c];
  }
  hmu[k] = tot * (1.0f / NDIM) * 0.1f + 0.01f;
}

// ---------------- scan phase 3: full scan with carry, write S_all [t][j] bf16 ----------------
__global__ __launch_bounds__(64) void k_phase3(const float* __restrict__ obs,
                                               const float* __restrict__ hbeta,
                                               const float* __restrict__ carry,
                                               bf16_t* __restrict__ S_all) {
  int c  = blockIdx.x & (CHUNKS - 1);
  int kb = blockIdx.x >> 8;
  int lane = threadIdx.x;
  float beta = hbeta[0];
  float decay = expf(-beta);
  __shared__ float  obs_s[64][65];
  __shared__ bf16_t out_s[64][72];
  int k0 = kb * 64, t0 = c * CLEN;
#pragma unroll 4
  for (int r = 0; r < 64; ++r)
    obs_s[r][lane] = obs[(size_t)(k0 + r) * NDIM + t0 + lane];
  __syncthreads();
  float S = carry[(size_t)(k0 + lane) * CHUNKS + c];
#pragma unroll 8
  for (int t = 0; t < CLEN; ++t) {
    out_s[t][lane] = (bf16_t)S;                 // S_all[t] is pre-update value
    S = decay * (S + beta * obs_s[lane][t]);
  }
  __syncthreads();
#pragma unroll 4
  for (int t = 0; t < CLEN; ++t)
    S_all[(size_t)(t0 + t) * KDIM + k0 + lane] = out_s[t][lane];
}

// ---------------- GEMM lam1 = halpha @ S_all^T, fused softplus + loglik ----------------
// 256x256 tile, BK=64, 512 threads (8 waves, 2Mx4N). Per K-tile: 4 phases, each
// {ds_read quadrant frags || stage gloads of next tile -> barrier -> setprio ->
//  16 MFMA -> setprio -> barrier}. vmcnt(0) once per tile before final barrier.
// LDS XOR-swizzle (slot ^= row&7) via pre-swizzled GLOBAL source + swizzled ds_read.
__global__ __launch_bounds__(512, 2) void k_gemm(const bf16_t* __restrict__ Ab,
                                                 const bf16_t* __restrict__ Bb,
                                                 const float* __restrict__ hmu,
                                                 const float* __restrict__ obs,
                                                 float* __restrict__ out) {
  __shared__ bf16_t As[2][256 * 64];
  __shared__ bf16_t Bs[2][256 * 64];
  int tid = threadIdx.x;
  // XCD-chunk swizzle: 256 blocks, 8 XCDs -> bijective
  int b = blockIdx.x;
  int lb = (b & 7) * 32 + (b >> 3);
  int kb = lb & 3;            // M-tile (4)
  int tb = lb >> 2;           // N-tile (64); 4 consecutive logical blocks share tb
  int lane = tid & 63, wid = tid >> 6;
  int wm = wid >> 2, wn = wid & 3;          // 2x4 waves, each 128x64 output
  int r15 = lane & 15, h = lane >> 4;
  f32x4 acc[8][4] = {};

  // staging: slot_id = i*512 + tid; row = slot_id>>3; phys slot sp = slot_id&7;
  // global source uses logical slot sl = sp ^ (row&7)  (inverse-swizzle the source)
  const bf16_t* gA[4];
  const bf16_t* gB[4];
#pragma unroll
  for (int i = 0; i < 4; ++i) {
    int slot = i * 512 + tid;
    int row = slot >> 3, sp = slot & 7;
    int sl = sp ^ (row & 7);
    gA[i] = Ab + (size_t)(kb * 256 + row) * KDIM + sl * 8;
    gB[i] = Bb + (size_t)(tb * 256 + row) * KDIM + sl * 8;
  }

#define STAGE_A(buf, kkoff) do { \
  _Pragma("unroll") \
  for (int i = 0; i < 4; ++i) \
    gload_lds16(gA[i] + (kkoff), &As[buf][(i * 512 + wid * 64) * 8]); \
} while (0)
#define STAGE_B(buf, kkoff) do { \
  _Pragma("unroll") \
  for (int i = 0; i < 4; ++i) \
    gload_lds16(gB[i] + (kkoff), &Bs[buf][(i * 512 + wid * 64) * 8]); \
} while (0)

  // prologue: stage tile 0, drain, publish
  STAGE_A(0, 0);
  STAGE_B(0, 0);
  asm volatile("s_waitcnt vmcnt(0)" ::: "memory");
  __builtin_amdgcn_s_barrier();

  int cur = 0;
  for (int kt = 0; kt < KTILES; ++kt) {
    bf16x8 bfr[4][2];
#pragma unroll
    for (int ph = 0; ph < 4; ++ph) {
      // --- ds_read this phase's fragments ---
      bf16x8 af[2][2];
      if (ph == 0) {
#pragma unroll
        for (int ni = 0; ni < 4; ++ni)
#pragma unroll
          for (int kh = 0; kh < 2; ++kh) {
            int row = wn * 64 + ni * 16 + r15;
            bfr[ni][kh] = *reinterpret_cast<const bf16x8*>(
                &Bs[cur][row * 64 + (((kh * 4 + h) ^ (row & 7)) * 8)]);
          }
      }
#pragma unroll
      for (int m2 = 0; m2 < 2; ++m2)
#pragma unroll
        for (int kh = 0; kh < 2; ++kh) {
          int row = wm * 128 + (ph * 2 + m2) * 16 + r15;
          af[m2][kh] = *reinterpret_cast<const bf16x8*>(
              &As[cur][row * 64 + (((kh * 4 + h) ^ (row & 7)) * 8)]);
        }
      // --- stage next tile (A-halves in ph0, B-halves in ph1) ---
      if (kt < KTILES - 1) {
        if (ph == 0) STAGE_A(cur ^ 1, (kt + 1) * 64);
        if (ph == 1) STAGE_B(cur ^ 1, (kt + 1) * 64);
      }
      // --- phase barrier, then MFMA cluster ---
      __builtin_amdgcn_s_barrier();
      __builtin_amdgcn_s_setprio(1);
#pragma unroll
      for (int m2 = 0; m2 < 2; ++m2)
#pragma unroll
        for (int ni = 0; ni < 4; ++ni)
#pragma unroll
          for (int kh = 0; kh < 2; ++kh)
            acc[ph * 2 + m2][ni] = __builtin_amdgcn_mfma_f32_16x16x32_bf16(
                af[m2][kh], bfr[ni][kh], acc[ph * 2 + m2][ni], 0, 0, 0);
      __builtin_amdgcn_s_setprio(0);
      if (ph == 3)  // drain next tile's stages before publishing barrier
        asm volatile("s_waitcnt vmcnt(0)" ::: "memory");
      __builtin_amdgcn_s_barrier();
    }
    cur ^= 1;
  }
#undef STAGE_A
#undef STAGE_B

  // epilogue: lams = softplus(hmu + lam1); loglik partial = obs*log(lams) - lams
  float lsum = 0.f;
  float* lams = out + 1;
#pragma unroll
  for (int mi = 0; mi < 8; ++mi) {
    int krow0 = kb * 256 + wm * 128 + mi * 16 + h * 4;
#pragma unroll
    for (int ni = 0; ni < 4; ++ni) {
      int t = tb * 256 + wn * 64 + ni * 16 + r15;
#pragma unroll
      for (int r = 0; r < 4; ++r) {
        int krow = krow0 + r;
        float x = hmu[krow] + acc[mi][ni][r];
        // stable cheap softplus: max(x,0) + log(1 + exp(-|x|))
        float lam = fmaxf(x, 0.f) + __logf(1.f + __expf(-fabsf(x)));
        lams[(size_t)krow * NDIM + t] = lam;
        float o = obs[(size_t)krow * NDIM + t];
        lsum += o * __logf(lam) - lam;
      }
    }
  }
  // reduce loglik
  lsum += __shfl_down(lsum, 32);
  lsum += __shfl_down(lsum, 16);
  lsum += __shfl_down(lsum, 8);
  lsum += __shfl_down(lsum, 4);
  lsum += __shfl_down(lsum, 2);
  lsum += __shfl_down(lsum, 1);
  __shared__ float wsum[8];
  if (lane == 0) wsum[wid] = lsum;
  __syncthreads();
  if (tid == 0) {
    float s = 0.f;
#pragma unroll
    for (int w = 0; w < 8; ++w) s += wsum[w];
    atomicAdd(out, s);
  }
}

extern "C" void kernel_launch(void* const* d_in, const int* in_sizes, int n_in,
                              void* d_out, int out_size, void* d_ws, size_t ws_size,
                              hipStream_t stream) {
  const float* obs    = (const float*)d_in[0];
  const float* halpha = (const float*)d_in[1];
  const float* hbeta  = (const float*)d_in[2];
  float* out = (float*)d_out;

  char* ws = (char*)d_ws;
  bf16_t* S_all = (bf16_t*)ws;                                   // 32 MB, [NDIM][KDIM]
  float*  carry = (float*)(ws + (size_t)NDIM * KDIM * 2);        // 1 MB, [K][CHUNKS]
  float*  psum  = carry + (size_t)KDIM * CHUNKS;                 // 1 MB
  float*  hmu   = psum + (size_t)KDIM * CHUNKS;                  // 4 KB
  bf16_t* Ab    = (bf16_t*)(hmu + KDIM);                         // 2 MB

  hipMemsetAsync(d_out, 0, sizeof(float), stream);               // loglik accumulator
  k_convert_alpha<<<(KDIM * KDIM) / (256 * 4), 256, 0, stream>>>(halpha, Ab);
  k_phase1<<<(KDIM * CHUNKS) / 256, 256, 0, stream>>>(obs, hbeta, carry, psum);
  k_phase2<<<16, 64, 0, stream>>>(hbeta, carry, psum, hmu);
  k_phase3<<<(KDIM / 64) * CHUNKS, 64, 0, stream>>>(obs, hbeta, carry, S_all);
  k_gemm<<<4 * (NDIM / 256), 512, 0, stream>>>(Ab, S_all, hmu, obs, out);
}